// Round 3
// baseline (1354.201 us; speedup 1.0000x reference)
//
#include <hip/hip_runtime.h>
#include <hip/hip_bf16.h>
#include <math.h>

#define D_MODEL 1024
#define N_HEAD  16
#define HEAD_DIM 64
#define T_SEQ   2048
#define BATCH   2

using f32x4  = __attribute__((ext_vector_type(4))) float;
using bf16x8 = __attribute__((ext_vector_type(8))) short;   // 8 bf16 in 4 VGPRs

__device__ __forceinline__ unsigned short f2bf(float f) {
    union { __hip_bfloat16 b; unsigned short u; } cv;
    cv.b = __float2bfloat16(f);   // RNE
    return cv.u;
}

// async global->LDS, 16B per lane; LDS dest must be wave-uniform base + lane*16
#define GLOAD16(g, l) __builtin_amdgcn_global_load_lds( \
    (const __attribute__((address_space(1))) void*)(g), \
    (__attribute__((address_space(3))) void*)(l), 16, 0, 0)

// ---------------------------------------------------------------------------
// fp32 -> bf16 cast (n multiple of 8)
// ---------------------------------------------------------------------------
__global__ __launch_bounds__(256)
void cast_f32_bf16_kernel(const float* __restrict__ in,
                          unsigned short* __restrict__ out, int n)
{
    int i = (blockIdx.x * 256 + threadIdx.x) * 8;
    if (i >= n) return;
    float4 v0 = *(const float4*)(in + i);
    float4 v1 = *(const float4*)(in + i + 4);
    ushort4 o0, o1;
    o0.x = f2bf(v0.x); o0.y = f2bf(v0.y); o0.z = f2bf(v0.z); o0.w = f2bf(v0.w);
    o1.x = f2bf(v1.x); o1.y = f2bf(v1.y); o1.z = f2bf(v1.z); o1.w = f2bf(v1.w);
    *(ushort4*)(out + i)     = o0;
    *(ushort4*)(out + i + 4) = o1;
}

// ---------------------------------------------------------------------------
// W[K][N] fp32  ->  Wt[N][K] bf16   (32x32 LDS tile, both sides coalesced)
// ---------------------------------------------------------------------------
__global__ __launch_bounds__(256)
void transpose_cast_kernel(const float* __restrict__ in,
                           unsigned short* __restrict__ out, int K, int N)
{
    __shared__ float tile[32][33];
    const int n0 = blockIdx.x * 32, k0 = blockIdx.y * 32;
    const int tx = threadIdx.x & 31, ty = threadIdx.x >> 5;   // 32 x 8
#pragma unroll
    for (int u = 0; u < 32; u += 8)
        tile[ty + u][tx] = in[(size_t)(k0 + ty + u) * N + n0 + tx];
    __syncthreads();
#pragma unroll
    for (int u = 0; u < 32; u += 8)
        out[(size_t)(n0 + ty + u) * K + k0 + tx] = f2bf(tile[tx][ty + u]);
}

// ---------------------------------------------------------------------------
// bf16 MFMA GEMM (m97 structure): C[M][N] = A[M][K] * Bt[N][K]^T + bias
// 128x128 tile, BK=32, 256 threads = 4 waves in 2x2, 16x16x32 MFMA,
// global_load_lds width=16 staging, 2 barriers per K-step.
// ---------------------------------------------------------------------------
__global__ __launch_bounds__(256)
void gemm_bf16_kernel(const unsigned short* __restrict__ A,   // [M][K] bf16
                      const unsigned short* __restrict__ Bt,  // [N][K] bf16
                      const float* __restrict__ bias,         // [N] fp32
                      float* __restrict__ C,                  // [M][N] fp32
                      int M, int N, int K)
{
    __shared__ unsigned short As[128 * 32];   // [m][k] 8KB
    __shared__ unsigned short Bs[128 * 32];   // [n][k] 8KB

    const int tid  = threadIdx.x;
    const int lane = tid & 63;
    const int wave = tid >> 6;
    const int wr = wave >> 1, wc = wave & 1;       // 2x2 wave grid, 64x64 each
    const int m0 = blockIdx.y * 128, n0 = blockIdx.x * 128;
    const int lo = lane & 15, hi = lane >> 4;

    // staging map: thread t covers row t>>2 (0..63), k-chunk (t&3)*8; 2 rounds
    const int lrow = tid >> 2;
    const int lcol = (tid & 3) * 8;
    const unsigned short* gA = A  + (size_t)(m0 + lrow) * K + lcol;
    const unsigned short* gB = Bt + (size_t)(n0 + lrow) * K + lcol;
    unsigned short* lA = As + tid * 8;   // byte offset tid*16 (linear)
    unsigned short* lB = Bs + tid * 8;

    f32x4 acc[4][4];
#pragma unroll
    for (int i = 0; i < 4; ++i)
#pragma unroll
        for (int j = 0; j < 4; ++j) acc[i][j] = (f32x4){0.f, 0.f, 0.f, 0.f};

    for (int k0 = 0; k0 < K; k0 += 32) {
        __syncthreads();                       // prev compute done reading LDS
        GLOAD16(gA + k0,           lA);
        GLOAD16(gA + (size_t)64 * K + k0, lA + 64 * 32);
        GLOAD16(gB + k0,           lB);
        GLOAD16(gB + (size_t)64 * K + k0, lB + 64 * 32);
        __syncthreads();                       // vmcnt(0) drain: tiles ready

        bf16x8 a[4], b[4];
#pragma unroll
        for (int i = 0; i < 4; ++i) {
            a[i] = *(const bf16x8*)(As + (wr * 64 + i * 16 + lo) * 32 + hi * 8);
            b[i] = *(const bf16x8*)(Bs + (wc * 64 + i * 16 + lo) * 32 + hi * 8);
        }
#pragma unroll
        for (int i = 0; i < 4; ++i)
#pragma unroll
            for (int j = 0; j < 4; ++j)
                acc[i][j] = __builtin_amdgcn_mfma_f32_16x16x32_bf16(
                                a[i], b[j], acc[i][j], 0, 0, 0);
    }

    // epilogue: C/D layout col=lane&15, row=(lane>>4)*4+reg  (HW-verified m89)
    float brg[4];
#pragma unroll
    for (int j = 0; j < 4; ++j) brg[j] = bias[n0 + wc * 64 + j * 16 + lo];
#pragma unroll
    for (int i = 0; i < 4; ++i)
#pragma unroll
        for (int j = 0; j < 4; ++j) {
            const int col = n0 + wc * 64 + j * 16 + lo;
#pragma unroll
            for (int q = 0; q < 4; ++q) {
                const int row = m0 + wr * 64 + i * 16 + hi * 4 + q;
                C[(size_t)row * N + col] = acc[i][j][q] + brg[j];
            }
        }
}

// ---------------------------------------------------------------------------
// Flash-style causal attention, fp32 compute, bf16 output.
// qkv: [B, T, 3C] fp32 (q at h*64, k at C+h*64, v at 2C+h*64)
// y:   [B, T, C] bf16
// ---------------------------------------------------------------------------
#define ATT_PAD 4

__global__ __launch_bounds__(256)
void attn_kernel(const float* __restrict__ qkv, unsigned short* __restrict__ y)
{
    __shared__ float Qs[64][64 + ATT_PAD];
    __shared__ float KPs[64][64 + ATT_PAD];  // K tile, reused for P
    __shared__ float Vs[64][64 + ATT_PAD];

    const int tid = threadIdx.x;
    const int qt = blockIdx.x;
    const int bh = blockIdx.y;
    const int b  = bh >> 4;
    const int h  = bh & 15;
    const int tx = tid & 15;
    const int ty = tid >> 4;

    const size_t bbase = (size_t)b * T_SEQ * (3 * D_MODEL);
    const int hoff = h * HEAD_DIM;

#pragma unroll
    for (int u = 0; u < 4; ++u) {
        int e = u * 256 + tid;
        int r = e >> 4, c = (e & 15) << 2;
        *(float4*)&Qs[r][c] =
            *(const float4*)&qkv[bbase + (size_t)(qt * 64 + r) * (3 * D_MODEL) + hoff + c];
    }

    float m_i[4], l_i[4], o[4][4];
#pragma unroll
    for (int i = 0; i < 4; ++i) {
        m_i[i] = -1e30f; l_i[i] = 0.0f;
#pragma unroll
        for (int c = 0; c < 4; ++c) o[i][c] = 0.0f;
    }

    for (int kt = 0; kt <= qt; ++kt) {
        __syncthreads();
#pragma unroll
        for (int u = 0; u < 4; ++u) {
            int e = u * 256 + tid;
            int r = e >> 4, c = (e & 15) << 2;
            size_t base = bbase + (size_t)(kt * 64 + r) * (3 * D_MODEL) + hoff + c;
            *(float4*)&KPs[r][c] = *(const float4*)&qkv[base + D_MODEL];
            *(float4*)&Vs[r][c]  = *(const float4*)&qkv[base + 2 * D_MODEL];
        }
        __syncthreads();

        float s[4][4];
#pragma unroll
        for (int i = 0; i < 4; ++i)
#pragma unroll
            for (int j = 0; j < 4; ++j) s[i][j] = 0.0f;

#pragma unroll
        for (int k4 = 0; k4 < 16; ++k4) {
            float qr[4][4], kc[4][4];
#pragma unroll
            for (int i = 0; i < 4; ++i) {
                float4 t = *(const float4*)&Qs[ty + 16 * i][k4 << 2];
                qr[i][0] = t.x; qr[i][1] = t.y; qr[i][2] = t.z; qr[i][3] = t.w;
            }
#pragma unroll
            for (int j = 0; j < 4; ++j) {
                float4 t = *(const float4*)&KPs[tx + 16 * j][k4 << 2];
                kc[j][0] = t.x; kc[j][1] = t.y; kc[j][2] = t.z; kc[j][3] = t.w;
            }
#pragma unroll
            for (int i = 0; i < 4; ++i)
#pragma unroll
                for (int j = 0; j < 4; ++j)
#pragma unroll
                    for (int u = 0; u < 4; ++u)
                        s[i][j] += qr[i][u] * kc[j][u];
        }

        const float scale = 0.125f;
#pragma unroll
        for (int i = 0; i < 4; ++i)
#pragma unroll
            for (int j = 0; j < 4; ++j) s[i][j] *= scale;

        if (kt == qt) {
#pragma unroll
            for (int i = 0; i < 4; ++i)
#pragma unroll
                for (int j = 0; j < 4; ++j)
                    if ((tx + 16 * j) > (ty + 16 * i)) s[i][j] = -1e30f;
        }

        float p[4][4], pscale[4];
#pragma unroll
        for (int i = 0; i < 4; ++i) {
            float rmax = fmaxf(fmaxf(s[i][0], s[i][1]), fmaxf(s[i][2], s[i][3]));
#pragma unroll
            for (int d = 1; d < 16; d <<= 1)
                rmax = fmaxf(rmax, __shfl_xor(rmax, d, 16));
            float mn = fmaxf(m_i[i], rmax);
            pscale[i] = __expf(m_i[i] - mn);
            m_i[i] = mn;
            float rsum = 0.0f;
#pragma unroll
            for (int j = 0; j < 4; ++j) {
                p[i][j] = __expf(s[i][j] - mn);
                rsum += p[i][j];
            }
#pragma unroll
            for (int d = 1; d < 16; d <<= 1)
                rsum += __shfl_xor(rsum, d, 16);
            l_i[i] = l_i[i] * pscale[i] + rsum;
#pragma unroll
            for (int c = 0; c < 4; ++c) o[i][c] *= pscale[i];
        }

        __syncthreads();
#pragma unroll
        for (int i = 0; i < 4; ++i)
#pragma unroll
            for (int j = 0; j < 4; ++j)
                KPs[ty + 16 * i][tx + 16 * j] = p[i][j];
        __syncthreads();

#pragma unroll
        for (int j4 = 0; j4 < 16; ++j4) {
            float pr[4][4], vr[4][4];
#pragma unroll
            for (int i = 0; i < 4; ++i) {
                float4 t = *(const float4*)&KPs[ty + 16 * i][j4 << 2];
                pr[i][0] = t.x; pr[i][1] = t.y; pr[i][2] = t.z; pr[i][3] = t.w;
            }
#pragma unroll
            for (int u = 0; u < 4; ++u) {
                float4 t = *(const float4*)&Vs[(j4 << 2) + u][tx << 2];
                vr[u][0] = t.x; vr[u][1] = t.y; vr[u][2] = t.z; vr[u][3] = t.w;
            }
#pragma unroll
            for (int i = 0; i < 4; ++i)
#pragma unroll
                for (int c = 0; c < 4; ++c)
#pragma unroll
                    for (int u = 0; u < 4; ++u)
                        o[i][c] += pr[i][u] * vr[u][c];
        }
    }

    // epilogue: normalize + store bf16
#pragma unroll
    for (int i = 0; i < 4; ++i) {
        const int qrow = qt * 64 + ty + 16 * i;
        const float inv = 1.0f / l_i[i];
        ushort4 ov;
        ov.x = f2bf(o[i][0] * inv); ov.y = f2bf(o[i][1] * inv);
        ov.z = f2bf(o[i][2] * inv); ov.w = f2bf(o[i][3] * inv);
        *(ushort4*)&y[((size_t)b * T_SEQ + qrow) * D_MODEL + hoff + (tx << 2)] = ov;
    }
}

// ---------------------------------------------------------------------------
extern "C" void kernel_launch(void* const* d_in, const int* in_sizes, int n_in,
                              void* d_out, int out_size, void* d_ws, size_t ws_size,
                              hipStream_t stream)
{
    const float* x      = (const float*)d_in[0];
    const float* W_attn = (const float*)d_in[1];
    const float* b_attn = (const float*)d_in[2];
    const float* W_proj = (const float*)d_in[3];
    const float* b_proj = (const float*)d_in[4];
    float* out = (float*)d_out;

    const int M = BATCH * T_SEQ;   // 4096
    const int C = D_MODEL;         // 1024

    // workspace carve-up (16B aligned throughout)
    char* w = (char*)d_ws;
    float*          qkv     = (float*)w;          w += (size_t)M * 3 * C * 4;  // 50.3 MB
    unsigned short* y_bf    = (unsigned short*)w; w += (size_t)M * C * 2;      //  8.4 MB
    unsigned short* x_bf    = (unsigned short*)w; w += (size_t)M * C * 2;      //  8.4 MB
    unsigned short* wt_attn = (unsigned short*)w; w += (size_t)3 * C * C * 2;  //  6.3 MB
    unsigned short* wt_proj = (unsigned short*)w; w += (size_t)C * C * 2;      //  2.1 MB

    // prep: casts + weight transposes
    cast_f32_bf16_kernel<<<(M * C) / (8 * 256), 256, 0, stream>>>(x, x_bf, M * C);
    transpose_cast_kernel<<<dim3(3 * C / 32, C / 32), 256, 0, stream>>>(W_attn, wt_attn, C, 3 * C);
    transpose_cast_kernel<<<dim3(C / 32, C / 32), 256, 0, stream>>>(W_proj, wt_proj, C, C);

    // qkv = x @ W_attn + b_attn   (fp32 out)
    gemm_bf16_kernel<<<dim3(3 * C / 128, M / 128), 256, 0, stream>>>(
        x_bf, wt_attn, b_attn, qkv, M, 3 * C, C);

    // flash causal attention (fp32 compute, bf16 out)
    attn_kernel<<<dim3(T_SEQ / 64, BATCH * N_HEAD), 256, 0, stream>>>(qkv, y_bf);

    // out = y @ W_proj + b_proj
    gemm_bf16_kernel<<<dim3(C / 128, M / 128), 256, 0, stream>>>(
        y_bf, wt_proj, b_proj, out, M, C, C);
}

// Round 14
// 289.951 us; speedup vs baseline: 4.6704x; 4.6704x over previous
//
#include <hip/hip_runtime.h>
#include <hip/hip_bf16.h>
#include <math.h>

#define D_MODEL 1024
#define N_HEAD  16
#define HEAD_DIM 64
#define T_SEQ   2048
#define BATCH   2
#define BH      (BATCH * N_HEAD)

using f32x4  = __attribute__((ext_vector_type(4))) float;
using bf16x8 = __attribute__((ext_vector_type(8))) short;   // 8 bf16 in 4 VGPRs

__device__ __forceinline__ unsigned short f2bf(float f) {
    union { __hip_bfloat16 b; unsigned short u; } cv;
    cv.b = __float2bfloat16(f);   // RNE
    return cv.u;
}

// async global->LDS, 16B per lane; LDS dest must be wave-uniform base + lane*16
#define GLOAD16(g, l) __builtin_amdgcn_global_load_lds( \
    (const __attribute__((address_space(1))) void*)(g), \
    (__attribute__((address_space(3))) void*)(l), 16, 0, 0)

// ---------------------------------------------------------------------------
// fp32 -> bf16 cast (n multiple of 8)
// ---------------------------------------------------------------------------
__global__ __launch_bounds__(256)
void cast_f32_bf16_kernel(const float* __restrict__ in,
                          unsigned short* __restrict__ out, int n)
{
    int i = (blockIdx.x * 256 + threadIdx.x) * 8;
    if (i >= n) return;
    float4 v0 = *(const float4*)(in + i);
    float4 v1 = *(const float4*)(in + i + 4);
    ushort4 o0, o1;
    o0.x = f2bf(v0.x); o0.y = f2bf(v0.y); o0.z = f2bf(v0.z); o0.w = f2bf(v0.w);
    o1.x = f2bf(v1.x); o1.y = f2bf(v1.y); o1.z = f2bf(v1.z); o1.w = f2bf(v1.w);
    *(ushort4*)(out + i)     = o0;
    *(ushort4*)(out + i + 4) = o1;
}

// ---------------------------------------------------------------------------
// W[K][N] fp32  ->  Wt[N][K] bf16
// ---------------------------------------------------------------------------
__global__ __launch_bounds__(256)
void transpose_cast_kernel(const float* __restrict__ in,
                           unsigned short* __restrict__ out, int K, int N)
{
    __shared__ float tile[32][33];
    const int n0 = blockIdx.x * 32, k0 = blockIdx.y * 32;
    const int tx = threadIdx.x & 31, ty = threadIdx.x >> 5;   // 32 x 8
#pragma unroll
    for (int u = 0; u < 32; u += 8)
        tile[ty + u][tx] = in[(size_t)(k0 + ty + u) * N + n0 + tx];
    __syncthreads();
#pragma unroll
    for (int u = 0; u < 32; u += 8)
        out[(size_t)(n0 + ty + u) * K + k0 + tx] = f2bf(tile[tx][ty + u]);
}

// ---------------------------------------------------------------------------
// V [BH][T][64] bf16 -> Vt [BH][64][T] bf16
// ---------------------------------------------------------------------------
__global__ __launch_bounds__(256)
void transpose_v_kernel(const unsigned short* __restrict__ V,
                        unsigned short* __restrict__ Vt)
{
    __shared__ unsigned short tile[64][65];
    const int bh = blockIdx.y;
    const int tt = blockIdx.x;            // 64-wide t tile
    const int c  = threadIdx.x & 63;
    const int r4 = threadIdx.x >> 6;      // 0..3
#pragma unroll
    for (int rr = 0; rr < 64; rr += 4) {
        int r = rr + r4;
        tile[r][c] = V[((size_t)bh * T_SEQ + tt * 64 + r) * 64 + c];
    }
    __syncthreads();
#pragma unroll
    for (int rr = 0; rr < 64; rr += 4) {
        int d = rr + r4;
        Vt[((size_t)bh * 64 + d) * T_SEQ + tt * 64 + c] = tile[c][d];
    }
}

// ---------------------------------------------------------------------------
// bf16 MFMA GEMM core (m97 structure), two epilogues.
// C = A[M][K] * Bt[N][K]^T + bias
// ---------------------------------------------------------------------------
#define GEMM_CORE(A_, Bt_, K_)                                               \
    __shared__ unsigned short As[128 * 32];                                  \
    __shared__ unsigned short Bs[128 * 32];                                  \
    const int tid  = threadIdx.x;                                            \
    const int lane = tid & 63;                                               \
    const int wave = tid >> 6;                                               \
    const int wr = wave >> 1, wc = wave & 1;                                 \
    const int m0 = blockIdx.y * 128, n0 = blockIdx.x * 128;                  \
    const int lo = lane & 15, hi = lane >> 4;                                \
    const int lrow = tid >> 2;                                               \
    const int lcol = (tid & 3) * 8;                                          \
    const unsigned short* gA = A_  + (size_t)(m0 + lrow) * K_ + lcol;        \
    const unsigned short* gB = Bt_ + (size_t)(n0 + lrow) * K_ + lcol;        \
    unsigned short* lA = As + tid * 8;                                       \
    unsigned short* lB = Bs + tid * 8;                                       \
    f32x4 acc[4][4];                                                         \
    _Pragma("unroll") for (int i = 0; i < 4; ++i)                            \
        _Pragma("unroll") for (int j = 0; j < 4; ++j)                        \
            acc[i][j] = (f32x4){0.f, 0.f, 0.f, 0.f};                         \
    for (int k0 = 0; k0 < K_; k0 += 32) {                                    \
        __syncthreads();                                                     \
        GLOAD16(gA + k0,                    lA);                             \
        GLOAD16(gA + (size_t)64 * K_ + k0,  lA + 64 * 32);                   \
        GLOAD16(gB + k0,                    lB);                             \
        GLOAD16(gB + (size_t)64 * K_ + k0,  lB + 64 * 32);                   \
        __syncthreads();                                                     \
        bf16x8 a[4], b[4];                                                   \
        _Pragma("unroll") for (int i = 0; i < 4; ++i) {                      \
            a[i] = *(const bf16x8*)(As + (wr * 64 + i * 16 + lo) * 32 + hi * 8); \
            b[i] = *(const bf16x8*)(Bs + (wc * 64 + i * 16 + lo) * 32 + hi * 8); \
        }                                                                    \
        _Pragma("unroll") for (int i = 0; i < 4; ++i)                        \
            _Pragma("unroll") for (int j = 0; j < 4; ++j)                    \
                acc[i][j] = __builtin_amdgcn_mfma_f32_16x16x32_bf16(         \
                                a[i], b[j], acc[i][j], 0, 0, 0);             \
    }

// GEMM -> fp32 C (projection)
__global__ __launch_bounds__(256)
void gemm_bf16_kernel(const unsigned short* __restrict__ A,
                      const unsigned short* __restrict__ Bt,
                      const float* __restrict__ bias,
                      float* __restrict__ C, int M, int N, int K)
{
    GEMM_CORE(A, Bt, K)
    float brg[4];
#pragma unroll
    for (int j = 0; j < 4; ++j) brg[j] = bias[n0 + wc * 64 + j * 16 + lo];
#pragma unroll
    for (int i = 0; i < 4; ++i)
#pragma unroll
        for (int j = 0; j < 4; ++j) {
            const int col = n0 + wc * 64 + j * 16 + lo;
#pragma unroll
            for (int q = 0; q < 4; ++q) {
                const int row = m0 + wr * 64 + i * 16 + hi * 4 + q;
                C[(size_t)row * N + col] = acc[i][j][q] + brg[j];
            }
        }
}

// GEMM -> separated bf16 q/k/v in [BH][T][64] layout (N = 3072 fixed)
__global__ __launch_bounds__(256)
void gemm_qkv_kernel(const unsigned short* __restrict__ A,
                     const unsigned short* __restrict__ Bt,
                     const float* __restrict__ bias,
                     unsigned short* __restrict__ qkv_sep, int M, int N, int K)
{
    GEMM_CORE(A, Bt, K)
    const size_t SEG = (size_t)BH * T_SEQ * 64;
#pragma unroll
    for (int i = 0; i < 4; ++i)
#pragma unroll
        for (int j = 0; j < 4; ++j) {
            const int col = n0 + wc * 64 + j * 16 + lo;
            const int which = col >> 10;
            const int hh = (col & 1023) >> 6;
            const int dd = col & 63;
            const float bv = bias[col];
#pragma unroll
            for (int q = 0; q < 4; ++q) {
                const int row = m0 + wr * 64 + i * 16 + hi * 4 + q;
                const int bb = row >> 11, tt = row & 2047;
                qkv_sep[which * SEG +
                        (((size_t)(bb * 16 + hh) * T_SEQ + tt) * 64 + dd)] =
                    f2bf(acc[i][j][q] + bv);
            }
        }
}

// ---------------------------------------------------------------------------
// MFMA flash attention (bf16 operands, fp32 softmax/accum).
// Q,K: [BH][T][64]; Vt: [BH][64][T]; y: [B*T][C] bf16.
// Block: 64 q-rows (4 waves x 16), KV tiles of 64, double-buffered LDS.
// LDS tiles XOR-swizzled via pre-swizzled global source (rule 21).
// ---------------------------------------------------------------------------
__global__ __launch_bounds__(256)
void attn_mfma_kernel(const unsigned short* __restrict__ Qg,
                      const unsigned short* __restrict__ Kg,
                      const unsigned short* __restrict__ Vtg,
                      unsigned short* __restrict__ y)
{
    __shared__ unsigned short Ks[2][64 * 64];   // [kv][d]  16 KB
    __shared__ unsigned short Vs[2][64 * 64];   // [d][kv]  16 KB
    __shared__ unsigned short Ps[4][16 * 64];   // per-wave P tile, 8 KB

    const int tid  = threadIdx.x;
    const int lane = tid & 63;
    const int w    = tid >> 6;
    const int lo   = lane & 15, hi = lane >> 4;
    const int qt = blockIdx.x, bh = blockIdx.y;
    const int b = bh >> 4, h = bh & 15;

    // staging: thread t -> tile row sr (and sr+32), 16B chunk (t&7)^(sr&7)
    const int sr  = tid >> 3;
    const int scs = ((tid & 7) ^ (sr & 7)) * 16;   // pre-swizzled source byte off

    const char* Kbase = (const char*)(Kg  + (size_t)bh * T_SEQ * 64);
    const char* Vbase = (const char*)(Vtg + (size_t)bh * 64 * T_SEQ);

#define STAGE(cur_, kt_) do {                                                 \
    const char* kg = Kbase + ((size_t)(kt_) * 64 + sr) * 128 + scs;           \
    const char* vg = Vbase + (size_t)sr * (T_SEQ * 2) + (size_t)(kt_) * 128 + scs; \
    GLOAD16(kg,                      &Ks[cur_][tid * 8]);                     \
    GLOAD16(kg + 32 * 128,           &Ks[cur_][2048 + tid * 8]);              \
    GLOAD16(vg,                      &Vs[cur_][tid * 8]);                     \
    GLOAD16(vg + (size_t)32 * T_SEQ * 2, &Vs[cur_][2048 + tid * 8]);          \
} while (0)

    // Q fragments held in registers (wave w owns q rows w*16..w*16+15)
    const int qrow = qt * 64 + w * 16 + lo;
    const unsigned short* qptr = Qg + ((size_t)bh * T_SEQ + qrow) * 64 + hi * 8;
    const bf16x8 qf0 = *(const bf16x8*)(qptr);
    const bf16x8 qf1 = *(const bf16x8*)(qptr + 32);

    float m_i[4], l_i[4];
    f32x4 o_acc[4];
#pragma unroll
    for (int r = 0; r < 4; ++r) {
        m_i[r] = -1e30f; l_i[r] = 0.0f;
        o_acc[r] = (f32x4){0.f, 0.f, 0.f, 0.f};
    }

    STAGE(0, 0);
    __syncthreads();          // drains vmcnt(0): tile 0 ready
    int cur = 0;

    unsigned short* Pw = &Ps[w][0];
    const int swz = (lo & 7) << 4;     // read-side XOR (byte)

    for (int kt = 0; kt <= qt; ++kt) {
        if (kt < qt) STAGE(cur ^ 1, kt + 1);   // prefetch stays in flight

        const unsigned short* Kl = Ks[cur];
        const unsigned short* Vl = Vs[cur];

        // ---- S = Q K^T (per wave: 16 q x 64 kv) ----
        f32x4 s_acc[4];
#pragma unroll
        for (int j = 0; j < 4; ++j) s_acc[j] = (f32x4){0.f, 0.f, 0.f, 0.f};
#pragma unroll
        for (int ks = 0; ks < 2; ++ks) {
            const int co = ((ks * 64 + hi * 16) ^ swz) >> 1;   // ushort off in row
            const bf16x8 qf = ks ? qf1 : qf0;
#pragma unroll
            for (int j = 0; j < 4; ++j) {
                bf16x8 kf = *(const bf16x8*)(Kl + (j * 16 + lo) * 64 + co);
                s_acc[j] = __builtin_amdgcn_mfma_f32_16x16x32_bf16(qf, kf, s_acc[j], 0, 0, 0);
            }
        }

        // ---- online softmax (C layout: lane holds q=hi*4+reg, kv=lo+16j) ----
#pragma unroll
        for (int reg = 0; reg < 4; ++reg) {
            const int q2 = hi * 4 + reg;                  // q within wave tile
            const int qg = qt * 64 + w * 16 + q2;         // global q
            float sv[4];
#pragma unroll
            for (int j = 0; j < 4; ++j) {
                float s = s_acc[j][reg] * 0.125f;
                if (kt == qt && (kt * 64 + lo + 16 * j) > qg) s = -1e30f;
                sv[j] = s;
            }
            float mx = fmaxf(fmaxf(sv[0], sv[1]), fmaxf(sv[2], sv[3]));
            mx = fmaxf(mx, __shfl_xor(mx, 1));
            mx = fmaxf(mx, __shfl_xor(mx, 2));
            mx = fmaxf(mx, __shfl_xor(mx, 4));
            mx = fmaxf(mx, __shfl_xor(mx, 8));
            const float mn  = fmaxf(m_i[reg], mx);
            const float psc = __expf(m_i[reg] - mn);
            m_i[reg] = mn;
            float sum = 0.f;
#pragma unroll
            for (int j = 0; j < 4; ++j) {
                const float p = __expf(sv[j] - mn);
                sum += p;
                const int kv = lo + 16 * j;
                Pw[(q2 * 128 + ((kv * 2) ^ ((q2 & 7) << 4))) >> 1] = f2bf(p);
            }
            sum += __shfl_xor(sum, 1);
            sum += __shfl_xor(sum, 2);
            sum += __shfl_xor(sum, 4);
            sum += __shfl_xor(sum, 8);
            l_i[reg] = l_i[reg] * psc + sum;
#pragma unroll
            for (int j = 0; j < 4; ++j) o_acc[j][reg] *= psc;
        }

        // wave-local fence: P writes visible before P reads (does NOT drain vmcnt)
        asm volatile("s_waitcnt lgkmcnt(0)" ::: "memory");
        __builtin_amdgcn_sched_barrier(0);

        // ---- O += P V ----
#pragma unroll
        for (int ks = 0; ks < 2; ++ks) {
            const int co = ((ks * 64 + hi * 16) ^ swz) >> 1;
            bf16x8 pf = *(const bf16x8*)(Pw + lo * 64 + co);
#pragma unroll
            for (int j = 0; j < 4; ++j) {
                bf16x8 vf = *(const bf16x8*)(Vl + (j * 16 + lo) * 64 + co);
                o_acc[j] = __builtin_amdgcn_mfma_f32_16x16x32_bf16(pf, vf, o_acc[j], 0, 0, 0);
            }
        }

        __syncthreads();   // drains vmcnt (next tile staged) + all LDS reads done
        cur ^= 1;
    }

    // ---- epilogue: normalize, store bf16 y[M][C] ----
#pragma unroll
    for (int reg = 0; reg < 4; ++reg) {
        const float inv = 1.0f / l_i[reg];
        const size_t row = (size_t)b * T_SEQ + qt * 64 + w * 16 + hi * 4 + reg;
#pragma unroll
        for (int j = 0; j < 4; ++j)
            y[row * D_MODEL + h * 64 + lo + 16 * j] = f2bf(o_acc[j][reg] * inv);
    }
#undef STAGE
}

// ---------------------------------------------------------------------------
extern "C" void kernel_launch(void* const* d_in, const int* in_sizes, int n_in,
                              void* d_out, int out_size, void* d_ws, size_t ws_size,
                              hipStream_t stream)
{
    const float* x      = (const float*)d_in[0];
    const float* W_attn = (const float*)d_in[1];
    const float* b_attn = (const float*)d_in[2];
    const float* W_proj = (const float*)d_in[3];
    const float* b_proj = (const float*)d_in[4];
    float* out = (float*)d_out;

    const int M = BATCH * T_SEQ;   // 4096
    const int C = D_MODEL;         // 1024
    const size_t SEG = (size_t)BH * T_SEQ * 64;   // 4,194,304 elems

    char* w = (char*)d_ws;
    unsigned short* qkv_sep = (unsigned short*)w; w += 3 * SEG * 2;           // 25.2 MB
    unsigned short* vt_bf   = (unsigned short*)w; w += SEG * 2;               //  8.4 MB
    unsigned short* y_bf    = (unsigned short*)w; w += (size_t)M * C * 2;     //  8.4 MB
    unsigned short* x_bf    = (unsigned short*)w; w += (size_t)M * C * 2;     //  8.4 MB
    unsigned short* wt_attn = (unsigned short*)w; w += (size_t)3 * C * C * 2; //  6.3 MB
    unsigned short* wt_proj = (unsigned short*)w; w += (size_t)C * C * 2;     //  2.1 MB

    cast_f32_bf16_kernel<<<(M * C) / (8 * 256), 256, 0, stream>>>(x, x_bf, M * C);
    transpose_cast_kernel<<<dim3(3 * C / 32, C / 32), 256, 0, stream>>>(W_attn, wt_attn, C, 3 * C);
    transpose_cast_kernel<<<dim3(C / 32, C / 32), 256, 0, stream>>>(W_proj, wt_proj, C, C);

    // qkv (separated bf16, head-major) = x @ W_attn + b_attn
    gemm_qkv_kernel<<<dim3(3 * C / 128, M / 128), 256, 0, stream>>>(
        x_bf, wt_attn, b_attn, qkv_sep, M, 3 * C, C);

    // Vt = V^T per head
    transpose_v_kernel<<<dim3(T_SEQ / 64, BH), 256, 0, stream>>>(qkv_sep + 2 * SEG, vt_bf);

    // flash attention (MFMA)
    attn_mfma_kernel<<<dim3(T_SEQ / 64, BH), 256, 0, stream>>>(
        qkv_sep, qkv_sep + SEG, vt_bf, y_bf);

    // out = y @ W_proj + b_proj
    gemm_bf16_kernel<<<dim3(C / 128, M / 128), 256, 0, stream>>>(
        y_bf, wt_proj, b_proj, out, M, C, C);
}

// Round 15
// 240.951 us; speedup vs baseline: 5.6202x; 1.2034x over previous
//
#include <hip/hip_runtime.h>
#include <hip/hip_bf16.h>
#include <math.h>

#define D_MODEL 1024
#define N_HEAD  16
#define HEAD_DIM 64
#define T_SEQ   2048
#define BATCH   2
#define BH      (BATCH * N_HEAD)
#define NQT     (T_SEQ / 64)   // 32 q-tiles

using f32x4  = __attribute__((ext_vector_type(4))) float;
using bf16x8 = __attribute__((ext_vector_type(8))) short;   // 8 bf16 in 4 VGPRs

__device__ __forceinline__ unsigned short f2bf(float f) {
    union { __hip_bfloat16 b; unsigned short u; } cv;
    cv.b = __float2bfloat16(f);   // RNE
    return cv.u;
}

// async global->LDS, 16B per lane; LDS dest must be wave-uniform base + lane*16
#define GLOAD16(g, l) __builtin_amdgcn_global_load_lds( \
    (const __attribute__((address_space(1))) void*)(g), \
    (__attribute__((address_space(3))) void*)(l), 16, 0, 0)

// ---------------------------------------------------------------------------
// fp32 -> bf16 cast (n multiple of 8)
// ---------------------------------------------------------------------------
__global__ __launch_bounds__(256)
void cast_f32_bf16_kernel(const float* __restrict__ in,
                          unsigned short* __restrict__ out, int n)
{
    int i = (blockIdx.x * 256 + threadIdx.x) * 8;
    if (i >= n) return;
    float4 v0 = *(const float4*)(in + i);
    float4 v1 = *(const float4*)(in + i + 4);
    ushort4 o0, o1;
    o0.x = f2bf(v0.x); o0.y = f2bf(v0.y); o0.z = f2bf(v0.z); o0.w = f2bf(v0.w);
    o1.x = f2bf(v1.x); o1.y = f2bf(v1.y); o1.z = f2bf(v1.z); o1.w = f2bf(v1.w);
    *(ushort4*)(out + i)     = o0;
    *(ushort4*)(out + i + 4) = o1;
}

// ---------------------------------------------------------------------------
// W[K][N] fp32  ->  Wt[N][K] bf16
// ---------------------------------------------------------------------------
__global__ __launch_bounds__(256)
void transpose_cast_kernel(const float* __restrict__ in,
                           unsigned short* __restrict__ out, int K, int N)
{
    __shared__ float tile[32][33];
    const int n0 = blockIdx.x * 32, k0 = blockIdx.y * 32;
    const int tx = threadIdx.x & 31, ty = threadIdx.x >> 5;   // 32 x 8
#pragma unroll
    for (int u = 0; u < 32; u += 8)
        tile[ty + u][tx] = in[(size_t)(k0 + ty + u) * N + n0 + tx];
    __syncthreads();
#pragma unroll
    for (int u = 0; u < 32; u += 8)
        out[(size_t)(n0 + ty + u) * K + k0 + tx] = f2bf(tile[tx][ty + u]);
}

// ---------------------------------------------------------------------------
// V [BH][T][64] bf16 -> Vt [BH][64][T] bf16
// ---------------------------------------------------------------------------
__global__ __launch_bounds__(256)
void transpose_v_kernel(const unsigned short* __restrict__ V,
                        unsigned short* __restrict__ Vt)
{
    __shared__ unsigned short tile[64][65];
    const int bh = blockIdx.y;
    const int tt = blockIdx.x;            // 64-wide t tile
    const int c  = threadIdx.x & 63;
    const int r4 = threadIdx.x >> 6;      // 0..3
#pragma unroll
    for (int rr = 0; rr < 64; rr += 4) {
        int r = rr + r4;
        tile[r][c] = V[((size_t)bh * T_SEQ + tt * 64 + r) * 64 + c];
    }
    __syncthreads();
#pragma unroll
    for (int rr = 0; rr < 64; rr += 4) {
        int d = rr + r4;
        Vt[((size_t)bh * 64 + d) * T_SEQ + tt * 64 + c] = tile[c][d];
    }
}

// ---------------------------------------------------------------------------
// bf16 MFMA GEMM core (m97 structure), two epilogues.
// C = A[M][K] * Bt[N][K]^T + bias
// ---------------------------------------------------------------------------
#define GEMM_CORE(A_, Bt_, K_)                                               \
    __shared__ unsigned short As[128 * 32];                                  \
    __shared__ unsigned short Bs[128 * 32];                                  \
    const int tid  = threadIdx.x;                                            \
    const int lane = tid & 63;                                               \
    const int wave = tid >> 6;                                               \
    const int wr = wave >> 1, wc = wave & 1;                                 \
    const int m0 = blockIdx.y * 128, n0 = blockIdx.x * 128;                  \
    const int lo = lane & 15, hi = lane >> 4;                                \
    const int lrow = tid >> 2;                                               \
    const int lcol = (tid & 3) * 8;                                          \
    const unsigned short* gA = A_  + (size_t)(m0 + lrow) * K_ + lcol;        \
    const unsigned short* gB = Bt_ + (size_t)(n0 + lrow) * K_ + lcol;        \
    unsigned short* lA = As + tid * 8;                                       \
    unsigned short* lB = Bs + tid * 8;                                       \
    f32x4 acc[4][4];                                                         \
    _Pragma("unroll") for (int i = 0; i < 4; ++i)                            \
        _Pragma("unroll") for (int j = 0; j < 4; ++j)                        \
            acc[i][j] = (f32x4){0.f, 0.f, 0.f, 0.f};                         \
    for (int k0 = 0; k0 < K_; k0 += 32) {                                    \
        __syncthreads();                                                     \
        GLOAD16(gA + k0,                    lA);                             \
        GLOAD16(gA + (size_t)64 * K_ + k0,  lA + 64 * 32);                   \
        GLOAD16(gB + k0,                    lB);                             \
        GLOAD16(gB + (size_t)64 * K_ + k0,  lB + 64 * 32);                   \
        __syncthreads();                                                     \
        bf16x8 a[4], b[4];                                                   \
        _Pragma("unroll") for (int i = 0; i < 4; ++i) {                      \
            a[i] = *(const bf16x8*)(As + (wr * 64 + i * 16 + lo) * 32 + hi * 8); \
            b[i] = *(const bf16x8*)(Bs + (wc * 64 + i * 16 + lo) * 32 + hi * 8); \
        }                                                                    \
        _Pragma("unroll") for (int i = 0; i < 4; ++i)                        \
            _Pragma("unroll") for (int j = 0; j < 4; ++j)                    \
                acc[i][j] = __builtin_amdgcn_mfma_f32_16x16x32_bf16(         \
                                a[i], b[j], acc[i][j], 0, 0, 0);             \
    }

// GEMM -> fp32 C (projection)
__global__ __launch_bounds__(256)
void gemm_bf16_kernel(const unsigned short* __restrict__ A,
                      const unsigned short* __restrict__ Bt,
                      const float* __restrict__ bias,
                      float* __restrict__ C, int M, int N, int K)
{
    GEMM_CORE(A, Bt, K)
    float brg[4];
#pragma unroll
    for (int j = 0; j < 4; ++j) brg[j] = bias[n0 + wc * 64 + j * 16 + lo];
#pragma unroll
    for (int i = 0; i < 4; ++i)
#pragma unroll
        for (int j = 0; j < 4; ++j) {
            const int col = n0 + wc * 64 + j * 16 + lo;
#pragma unroll
            for (int q = 0; q < 4; ++q) {
                const int row = m0 + wr * 64 + i * 16 + hi * 4 + q;
                C[(size_t)row * N + col] = acc[i][j][q] + brg[j];
            }
        }
}

// GEMM -> separated bf16 q/k/v in [BH][T][64] layout (N = 3072 fixed)
__global__ __launch_bounds__(256)
void gemm_qkv_kernel(const unsigned short* __restrict__ A,
                     const unsigned short* __restrict__ Bt,
                     const float* __restrict__ bias,
                     unsigned short* __restrict__ qkv_sep, int M, int N, int K)
{
    GEMM_CORE(A, Bt, K)
    const size_t SEG = (size_t)BH * T_SEQ * 64;
#pragma unroll
    for (int i = 0; i < 4; ++i)
#pragma unroll
        for (int j = 0; j < 4; ++j) {
            const int col = n0 + wc * 64 + j * 16 + lo;
            const int which = col >> 10;
            const int hh = (col & 1023) >> 6;
            const int dd = col & 63;
            const float bv = bias[col];
#pragma unroll
            for (int q = 0; q < 4; ++q) {
                const int row = m0 + wr * 64 + i * 16 + hi * 4 + q;
                const int bb = row >> 11, tt = row & 2047;
                qkv_sep[which * SEG +
                        (((size_t)(bb * 16 + hh) * T_SEQ + tt) * 64 + dd)] =
                    f2bf(acc[i][j][q] + bv);
            }
        }
}

// ---------------------------------------------------------------------------
// MFMA flash attention (bf16 operands, fp32 softmax/accum).
// Q,K: [BH][T][64]; Vt: [BH][64][T]; y: [B*T][C] bf16.
// Causal load balance: block bx handles q-tiles bx and NQT-1-bx (33 KV-tile
// iterations for every block). 4 waves x 16 q-rows, double-buffered LDS,
// XOR-swizzle via pre-swizzled global source (rule 21), setprio on MFMA (T5).
// ---------------------------------------------------------------------------
__global__ __launch_bounds__(256)
void attn_mfma_kernel(const unsigned short* __restrict__ Qg,
                      const unsigned short* __restrict__ Kg,
                      const unsigned short* __restrict__ Vtg,
                      unsigned short* __restrict__ y)
{
    __shared__ unsigned short Ks[2][64 * 64];   // [kv][d]  16 KB
    __shared__ unsigned short Vs[2][64 * 64];   // [d][kv]  16 KB
    __shared__ unsigned short Ps[4][16 * 64];   // per-wave P tile, 8 KB

    const int tid  = threadIdx.x;
    const int lane = tid & 63;
    const int w    = tid >> 6;
    const int lo   = lane & 15, hi = lane >> 4;
    const int bx = blockIdx.x, bh = blockIdx.y;
    const int b = bh >> 4, h = bh & 15;

    // staging: thread t -> tile row sr (and sr+32), 16B chunk (t&7)^(sr&7)
    const int sr  = tid >> 3;
    const int scs = ((tid & 7) ^ (sr & 7)) * 16;   // pre-swizzled source byte off

    const char* Kbase = (const char*)(Kg  + (size_t)bh * T_SEQ * 64);
    const char* Vbase = (const char*)(Vtg + (size_t)bh * 64 * T_SEQ);

#define STAGE(cur_, kt_) do {                                                 \
    const char* kg = Kbase + ((size_t)(kt_) * 64 + sr) * 128 + scs;           \
    const char* vg = Vbase + (size_t)sr * (T_SEQ * 2) + (size_t)(kt_) * 128 + scs; \
    GLOAD16(kg,                      &Ks[cur_][tid * 8]);                     \
    GLOAD16(kg + 32 * 128,           &Ks[cur_][2048 + tid * 8]);              \
    GLOAD16(vg,                      &Vs[cur_][tid * 8]);                     \
    GLOAD16(vg + (size_t)32 * T_SEQ * 2, &Vs[cur_][2048 + tid * 8]);          \
} while (0)

    unsigned short* Pw = &Ps[w][0];
    const int swz = (lo & 7) << 4;     // read-side XOR (byte)

    for (int ph = 0; ph < 2; ++ph) {
        const int qt = ph ? (NQT - 1 - bx) : bx;

        // Q fragments in registers (wave w owns q rows w*16..w*16+15)
        const int qrow = qt * 64 + w * 16 + lo;
        const unsigned short* qptr = Qg + ((size_t)bh * T_SEQ + qrow) * 64 + hi * 8;
        const bf16x8 qf0 = *(const bf16x8*)(qptr);
        const bf16x8 qf1 = *(const bf16x8*)(qptr + 32);

        float m_i[4], l_i[4];
        f32x4 o_acc[4];
#pragma unroll
        for (int r = 0; r < 4; ++r) {
            m_i[r] = -1e30f; l_i[r] = 0.0f;
            o_acc[r] = (f32x4){0.f, 0.f, 0.f, 0.f};
        }

        STAGE(0, 0);
        __syncthreads();          // drains vmcnt(0): tile 0 ready
        int cur = 0;

        for (int kt = 0; kt <= qt; ++kt) {
            if (kt < qt) STAGE(cur ^ 1, kt + 1);   // prefetch stays in flight

            const unsigned short* Kl = Ks[cur];
            const unsigned short* Vl = Vs[cur];

            // ---- S = Q K^T (per wave: 16 q x 64 kv) ----
            f32x4 s_acc[4];
#pragma unroll
            for (int j = 0; j < 4; ++j) s_acc[j] = (f32x4){0.f, 0.f, 0.f, 0.f};
            __builtin_amdgcn_s_setprio(1);
#pragma unroll
            for (int ks = 0; ks < 2; ++ks) {
                const int co = ((ks * 64 + hi * 16) ^ swz) >> 1;   // ushort off
                const bf16x8 qf = ks ? qf1 : qf0;
#pragma unroll
                for (int j = 0; j < 4; ++j) {
                    bf16x8 kf = *(const bf16x8*)(Kl + (j * 16 + lo) * 64 + co);
                    s_acc[j] = __builtin_amdgcn_mfma_f32_16x16x32_bf16(qf, kf, s_acc[j], 0, 0, 0);
                }
            }
            __builtin_amdgcn_s_setprio(0);

            // ---- online softmax (C layout: lane holds q=hi*4+reg, kv=lo+16j) ----
#pragma unroll
            for (int reg = 0; reg < 4; ++reg) {
                const int q2 = hi * 4 + reg;                  // q within wave tile
                const int qg = qt * 64 + w * 16 + q2;         // global q
                float sv[4];
#pragma unroll
                for (int j = 0; j < 4; ++j) {
                    float s = s_acc[j][reg] * 0.125f;
                    if (kt == qt && (kt * 64 + lo + 16 * j) > qg) s = -1e30f;
                    sv[j] = s;
                }
                float mx = fmaxf(fmaxf(sv[0], sv[1]), fmaxf(sv[2], sv[3]));
                mx = fmaxf(mx, __shfl_xor(mx, 1));
                mx = fmaxf(mx, __shfl_xor(mx, 2));
                mx = fmaxf(mx, __shfl_xor(mx, 4));
                mx = fmaxf(mx, __shfl_xor(mx, 8));
                const float mn  = fmaxf(m_i[reg], mx);
                const float psc = __expf(m_i[reg] - mn);
                m_i[reg] = mn;
                float sum = 0.f;
#pragma unroll
                for (int j = 0; j < 4; ++j) {
                    const float p = __expf(sv[j] - mn);
                    sum += p;
                    const int kv = lo + 16 * j;
                    Pw[(q2 * 128 + ((kv * 2) ^ ((q2 & 7) << 4))) >> 1] = f2bf(p);
                }
                sum += __shfl_xor(sum, 1);
                sum += __shfl_xor(sum, 2);
                sum += __shfl_xor(sum, 4);
                sum += __shfl_xor(sum, 8);
                l_i[reg] = l_i[reg] * psc + sum;
#pragma unroll
                for (int j = 0; j < 4; ++j) o_acc[j][reg] *= psc;
            }

            // wave-local fence: P writes visible before P reads (no vmcnt drain)
            asm volatile("s_waitcnt lgkmcnt(0)" ::: "memory");
            __builtin_amdgcn_sched_barrier(0);

            // ---- O += P V ----
            __builtin_amdgcn_s_setprio(1);
#pragma unroll
            for (int ks = 0; ks < 2; ++ks) {
                const int co = ((ks * 64 + hi * 16) ^ swz) >> 1;
                bf16x8 pf = *(const bf16x8*)(Pw + lo * 64 + co);
#pragma unroll
                for (int j = 0; j < 4; ++j) {
                    bf16x8 vf = *(const bf16x8*)(Vl + (j * 16 + lo) * 64 + co);
                    o_acc[j] = __builtin_amdgcn_mfma_f32_16x16x32_bf16(pf, vf, o_acc[j], 0, 0, 0);
                }
            }
            __builtin_amdgcn_s_setprio(0);

            __syncthreads();   // drains vmcnt (next tile staged) + LDS reads done
            cur ^= 1;
        }

        // ---- epilogue: normalize, store bf16 y[M][C] ----
#pragma unroll
        for (int reg = 0; reg < 4; ++reg) {
            const float inv = 1.0f / l_i[reg];
            const size_t row = (size_t)b * T_SEQ + qt * 64 + w * 16 + hi * 4 + reg;
#pragma unroll
            for (int j = 0; j < 4; ++j)
                y[row * D_MODEL + h * 64 + lo + 16 * j] = f2bf(o_acc[j][reg] * inv);
        }
    }
#undef STAGE
}

// ---------------------------------------------------------------------------
extern "C" void kernel_launch(void* const* d_in, const int* in_sizes, int n_in,
                              void* d_out, int out_size, void* d_ws, size_t ws_size,
                              hipStream_t stream)
{
    const float* x      = (const float*)d_in[0];
    const float* W_attn = (const float*)d_in[1];
    const float* b_attn = (const float*)d_in[2];
    const float* W_proj = (const float*)d_in[3];
    const float* b_proj = (const float*)d_in[4];
    float* out = (float*)d_out;

    const int M = BATCH * T_SEQ;   // 4096
    const int C = D_MODEL;         // 1024
    const size_t SEG = (size_t)BH * T_SEQ * 64;   // 4,194,304 elems

    char* w = (char*)d_ws;
    unsigned short* qkv_sep = (unsigned short*)w; w += 3 * SEG * 2;           // 25.2 MB
    unsigned short* vt_bf   = (unsigned short*)w; w += SEG * 2;               //  8.4 MB
    unsigned short* y_bf    = (unsigned short*)w; w += (size_t)M * C * 2;     //  8.4 MB
    unsigned short* x_bf    = (unsigned short*)w; w += (size_t)M * C * 2;     //  8.4 MB
    unsigned short* wt_attn = (unsigned short*)w; w += (size_t)3 * C * C * 2; //  6.3 MB
    unsigned short* wt_proj = (unsigned short*)w; w += (size_t)C * C * 2;     //  2.1 MB

    cast_f32_bf16_kernel<<<(M * C) / (8 * 256), 256, 0, stream>>>(x, x_bf, M * C);
    transpose_cast_kernel<<<dim3(3 * C / 32, C / 32), 256, 0, stream>>>(W_attn, wt_attn, C, 3 * C);
    transpose_cast_kernel<<<dim3(C / 32, C / 32), 256, 0, stream>>>(W_proj, wt_proj, C, C);

    // qkv (separated bf16, head-major) = x @ W_attn + b_attn
    gemm_qkv_kernel<<<dim3(3 * C / 128, M / 128), 256, 0, stream>>>(
        x_bf, wt_attn, b_attn, qkv_sep, M, 3 * C, C);

    // Vt = V^T per head
    transpose_v_kernel<<<dim3(T_SEQ / 64, BH), 256, 0, stream>>>(qkv_sep + 2 * SEG, vt_bf);

    // flash attention (MFMA, qt-paired for causal load balance)
    attn_mfma_kernel<<<dim3(NQT / 2, BH), 256, 0, stream>>>(
        qkv_sep, qkv_sep + SEG, vt_bf, y_bf);

    // out = y @ W_proj + b_proj
    gemm_bf16_kernel<<<dim3(C / 128, M / 128), 256, 0, stream>>>(
        y_bf, wt_proj, b_proj, out, M, C, C);
}